// Round 6
// baseline (679.256 us; speedup 1.0000x reference)
//
#include <hip/hip_runtime.h>

// HDC token encoder: out[b,i,d] = item_memory[token_ids[b,i]][(d - i) mod D] * 0.01f
// B=8, S=2048, V=256, D=10000. Every +/-1 row has L2 norm exactly 100, so the
// normalize is a constant scale by 0.01f (bit-exact vs reference, verified R0).
//
// Harness accounting (R5): timed region carries ~531 us of fixed poison-fill
// overhead (2.62 GB ws + 655 MB d_out); our kernel is total - 531.
//
// R6: 16 rows per block, register-double-buffered row pipeline. gather(row k+1)
// is issued before emit(row k), so the next row's gather loads are in flight
// under the current row's nontemporal store burst — the store stream never
// stalls on load latency, approximating the poison-fill's continuous
// fire-and-forget store pattern (6.2 TB/s).

#define B_  8
#define S_  2048
#define D_  10000
#define NCH 10                           // ceil(2500 chunks / 256 threads)
#define RPB 16                           // rows per block

typedef float vf4  __attribute__((ext_vector_type(4)));              // 16B aligned
typedef float vf4u __attribute__((ext_vector_type(4), aligned(4)));  // 4B aligned

__global__ __launch_bounds__(256) void hdc_encode(
    const int* __restrict__ token_ids,
    const float* __restrict__ item_memory,
    float* __restrict__ out)
{
    const int tid  = threadIdx.x;
    const int row0 = blockIdx.x * RPB;
    // chunks c = tid + 256*j, j in [0, nj); 2500 = 9*256 + 196
    const int nj = (tid < 2500 - 9 * 256) ? NCH : NCH - 1;

    // Gather one row's 10 float4 fragments into registers.
    // s_j = (4*tid - i + 1024*j) mod D; at most one j takes the wrap path.
    auto gather = [&](int row, vf4* v) {
        const int   i   = row & (S_ - 1);
        const int   tok = token_ids[row];                 // block-uniform scalar load
        const float* __restrict__ src = item_memory + (size_t)tok * D_;
        int s = 4 * tid - i;
        if (s < 0) s += D_;
        #pragma unroll
        for (int j = 0; j < NCH; ++j) {
            if (j < nj) {
                if (s <= D_ - 4) {
                    v[j] = *reinterpret_cast<const vf4u*>(src + s);  // 4B-aligned dwordx4
                } else {
                    int s1 = s + 1; if (s1 >= D_) s1 -= D_;
                    int s2 = s + 2; if (s2 >= D_) s2 -= D_;
                    int s3 = s + 3; if (s3 >= D_) s3 -= D_;
                    v[j].x = src[s]; v[j].y = src[s1]; v[j].z = src[s2]; v[j].w = src[s3];
                }
            }
            s += 1024;                    // 4 * 256
            if (s >= D_) s -= D_;
        }
    };

    // Fire-and-forget nontemporal store burst (1KB contiguous per wave-instr).
    auto emit = [&](int row, vf4* v) {
        vf4* __restrict__ dst4 = reinterpret_cast<vf4*>(out + (size_t)row * D_);
        #pragma unroll
        for (int j = 0; j < NCH; ++j) {
            if (j < nj) {
                __builtin_nontemporal_store(v[j] * 0.01f, dst4 + tid + 256 * j);
            }
        }
    };

    vf4 cur[NCH], nxt[NCH];

    gather(row0, cur);
    // Unrolled-by-2 ping-pong: no register copies, gather(k+1) precedes emit(k).
    for (int k = 0; k < RPB - 2; k += 2) {
        gather(row0 + k + 1, nxt);
        emit(row0 + k, cur);
        gather(row0 + k + 2, cur);
        emit(row0 + k + 1, nxt);
    }
    gather(row0 + RPB - 1, nxt);
    emit(row0 + RPB - 2, cur);
    emit(row0 + RPB - 1, nxt);
}

extern "C" void kernel_launch(void* const* d_in, const int* in_sizes, int n_in,
                              void* d_out, int out_size, void* d_ws, size_t ws_size,
                              hipStream_t stream)
{
    const int*   token_ids   = (const int*)d_in[0];
    const float* item_memory = (const float*)d_in[1];
    float*       out         = (float*)d_out;

    hdc_encode<<<dim3(B_ * S_ / RPB), dim3(256), 0, stream>>>(token_ids, item_memory, out);
}